// Round 2
// 342.499 us; speedup vs baseline: 1.0417x; 1.0417x over previous
//
#include <hip/hip_runtime.h>

// Problem constants
#define T_STEPS 8
#define NROW    42            // C*Dp = 3*14
#define BN      2688          // B*NROW = 64*42
#define H0      256
#define H1      128
#define KFLAT   5376          // NROW*H1

// Row layout is t-minor: m = (b*42 + c*14 + dp)*8 + t, so each thread's
// micro-tile rows are one neuron-group's full time axis and both LIF
// recurrences run in GEMM epilogue registers (bit-identical chain).

// LDS column swizzle: +4 floats every 32 -> stride-8/4 read groups conflict-free
#define SWA(r)  ((r) + ((r) >> 5) * 4)

// ---------------------------------------------------------------------------
// K1: FUSED avg-pool3d -> fc_in -> LIF -> fc_hid -> LIF -> spk_hid.
// 672 blocks x 256 threads; each block owns 4 neuron-groups x 8 timesteps
// (32 t-minor rows) and the full h0=256 / h1=128 axes, so spk_in lives only
// in registers/LDS and never touches HBM (saves 44 MB + a 5-wave/CU launch).
// 672 blocks also cuts the CU load imbalance: 2.625 blocks/CU (max 3) vs the
// old 336-block config's 1.31 (max 2).
// Phase A: 32x256 GEMM vs W_in, 8x4 micro; pooling add order and k-ascending
// fmaf order match the reference bitwise. Phase B: 32x128 GEMM vs W_hid,
// 8x2 micro, k-ascending in 16-chunks == old K2's exact order.
// ---------------------------------------------------------------------------
__global__ __launch_bounds__(256, 3) void snn_front(
        const float* __restrict__ x,
        const float* __restrict__ Wi,     // W_in  [256][256]
        const float* __restrict__ bi,
        const float* __restrict__ beti,
        const float* __restrict__ thri,
        const float* __restrict__ Wh,     // W_hid [128][256]
        const float* __restrict__ bh,
        const float* __restrict__ beth,
        const float* __restrict__ thrh,
        float* __restrict__ spkh) {       // [21504][128], t-minor rows
    // LDS plan (floats): S [256][36] spike matrix (k-major) aliases the
    // phase-A staging buffers (At [16][36] + Bt [16][284] = 5120 <= 9216);
    // Bt2 [16][140] sits after S. Total 45,824 B -> 3 blocks/CU.
    __shared__ float smem[9216 + 2240];
    float* S   = smem;
    float* At  = smem;
    float* Bt  = smem + 576;
    float* Bt2 = smem + 9216;

    int tid = threadIdx.x;
    int gbase = blockIdx.x * 4;           // 4 neuron-groups per block

    // ---- A staging map: 2 pooled elements per thread per k-chunk ----
    int wp = tid & 15;                    // k-within-chunk == wp
    int q  = tid >> 4;                    // 0..15
    const float* xb0;
    const float* xb1;
    int mloc0 = q * 2, mloc1 = q * 2 + 1; // 0..31
    {
        int g = gbase + (mloc0 >> 3);
        int t = mloc0 & 7;
        int b = g / 42, r = g - b * 42;
        int c = r / 14, dp = r - c * 14;
        xb0 = x + ((long)b * 712704 + (long)c * 237568
                + (long)(t * 29 + 2 * dp) * 1024 + 2 * wp);
    }
    {
        int g = gbase + (mloc1 >> 3);
        int t = mloc1 & 7;
        int b = g / 42, r = g - b * 42;
        int c = r / 14, dp = r - c * 14;
        xb1 = x + ((long)b * 712704 + (long)c * 237568
                + (long)(t * 29 + 2 * dp) * 1024 + 2 * wp);
    }

    // ---- B staging map (phase A): one W_in row per thread, 16 k/chunk ----
    const float* Bp = Wi + (long)tid * 256;
    int bcol = SWA(tid);

    // ---- compute map: 4 row-groups x 64 col-quads ----
    int tm = tid & 3;                     // row-group: rows tm*8 + t
    int tn = tid >> 2;                    // 0..63
    int ca = tm * 8;                      // SWA identity for m < 32
    int cb = SWA(tn * 4);

    float acc[8][4] = {};

    for (int k0 = 0; k0 < 256; k0 += 16) {
        int hp = k0 >> 4;
        const float* p0 = xb0 + hp * 64;
        const float* p1 = xb1 + hp * 64;
        float2 a00 = *(const float2*)(p0);
        float2 a01 = *(const float2*)(p0 + 32);
        float2 a02 = *(const float2*)(p0 + 1024);
        float2 a03 = *(const float2*)(p0 + 1056);
        float2 a10 = *(const float2*)(p1);
        float2 a11 = *(const float2*)(p1 + 32);
        float2 a12 = *(const float2*)(p1 + 1024);
        float2 a13 = *(const float2*)(p1 + 1056);
        float4 w0 = *(const float4*)(Bp + k0);
        float4 w1 = *(const float4*)(Bp + k0 + 4);
        float4 w2 = *(const float4*)(Bp + k0 + 8);
        float4 w3 = *(const float4*)(Bp + k0 + 12);
        __syncthreads();
        // pooled values, exact reference add order
        float s0 = a00.x + a00.y + a01.x + a01.y + a02.x + a02.y + a03.x + a03.y;
        float s1 = a10.x + a10.y + a11.x + a11.y + a12.x + a12.y + a13.x + a13.y;
        At[wp * 36 + mloc0] = s0 * 0.125f;
        At[wp * 36 + mloc1] = s1 * 0.125f;
        Bt[ 0 * 284 + bcol] = w0.x; Bt[ 1 * 284 + bcol] = w0.y;
        Bt[ 2 * 284 + bcol] = w0.z; Bt[ 3 * 284 + bcol] = w0.w;
        Bt[ 4 * 284 + bcol] = w1.x; Bt[ 5 * 284 + bcol] = w1.y;
        Bt[ 6 * 284 + bcol] = w1.z; Bt[ 7 * 284 + bcol] = w1.w;
        Bt[ 8 * 284 + bcol] = w2.x; Bt[ 9 * 284 + bcol] = w2.y;
        Bt[10 * 284 + bcol] = w2.z; Bt[11 * 284 + bcol] = w2.w;
        Bt[12 * 284 + bcol] = w3.x; Bt[13 * 284 + bcol] = w3.y;
        Bt[14 * 284 + bcol] = w3.z; Bt[15 * 284 + bcol] = w3.w;
        __syncthreads();
#pragma unroll
        for (int k = 0; k < 16; ++k) {
            float4 av0 = *(const float4*)&At[k * 36 + ca];
            float4 av1 = *(const float4*)&At[k * 36 + ca + 4];
            float4 bv  = *(const float4*)&Bt[k * 284 + cb];
            float am[8] = {av0.x, av0.y, av0.z, av0.w, av1.x, av1.y, av1.z, av1.w};
            float bb[4] = {bv.x, bv.y, bv.z, bv.w};
#pragma unroll
            for (int i = 0; i < 8; ++i)
#pragma unroll
                for (int j = 0; j < 4; ++j)
                    acc[i][j] = fmaf(am[i], bb[j], acc[i][j]);
        }
    }

    // ---- LIF-in epilogue: acc[t][j] -> spike values (bit-identical) ----
#pragma unroll
    for (int j = 0; j < 4; ++j) {
        int h = tn * 4 + j;
        float be = fminf(fmaxf(beti[h], 0.f), 1.f);
        float th = thri[h];
        float bb = bi[h];
        float mem = 0.f;
#pragma unroll
        for (int t = 0; t < T_STEPS; ++t) {
            float cur = acc[t][j] + bb;
            float reset = (mem > th) ? th : 0.f;
            mem = be * mem + cur - reset;
            acc[t][j] = ((mem - th) > 0.f) ? 1.f : 0.f;
        }
    }

    // ---- spike matrix to LDS (k-major), aliasing At/Bt after a barrier ----
    __syncthreads();                      // all phase-A LDS reads are done
#pragma unroll
    for (int j = 0; j < 4; ++j) {
        int h = tn * 4 + j;
#pragma unroll
        for (int t = 0; t < T_STEPS; ++t)
            S[h * 36 + ca + t] = acc[t][j];
    }
    // visibility of S is covered by the first barrier inside the phase-B loop

    // ---- Phase B: cur_hid = spk_in @ W_hid^T, 8x2 micro ----
    const float* Bp2 = Wh + (long)(tid >> 1) * 256 + (tid & 1) * 8;
    int bcol2 = SWA(tid >> 1);
    int cb2 = SWA(tn * 2);
    float acc2[8][2] = {};

    for (int k0 = 0; k0 < 256; k0 += 16) {
        float4 u0 = *(const float4*)(Bp2 + k0);
        float4 u1 = *(const float4*)(Bp2 + k0 + 4);
        __syncthreads();
        int kb = (tid & 1) * 8;
        Bt2[(kb + 0) * 140 + bcol2] = u0.x; Bt2[(kb + 1) * 140 + bcol2] = u0.y;
        Bt2[(kb + 2) * 140 + bcol2] = u0.z; Bt2[(kb + 3) * 140 + bcol2] = u0.w;
        Bt2[(kb + 4) * 140 + bcol2] = u1.x; Bt2[(kb + 5) * 140 + bcol2] = u1.y;
        Bt2[(kb + 6) * 140 + bcol2] = u1.z; Bt2[(kb + 7) * 140 + bcol2] = u1.w;
        __syncthreads();
#pragma unroll
        for (int k = 0; k < 16; ++k) {
            float4 av0 = *(const float4*)&S[(k0 + k) * 36 + ca];
            float4 av1 = *(const float4*)&S[(k0 + k) * 36 + ca + 4];
            float2 bv  = *(const float2*)&Bt2[k * 140 + cb2];
            float am[8] = {av0.x, av0.y, av0.z, av0.w, av1.x, av1.y, av1.z, av1.w};
#pragma unroll
            for (int i = 0; i < 8; ++i) {
                acc2[i][0] = fmaf(am[i], bv.x, acc2[i][0]);
                acc2[i][1] = fmaf(am[i], bv.y, acc2[i][1]);
            }
        }
    }

    // ---- LIF-hid epilogue + store spk_hid (t-minor rows) ----
#pragma unroll
    for (int j = 0; j < 2; ++j) {
        int h = tn * 2 + j;
        float be = fminf(fmaxf(beth[h], 0.f), 1.f);
        float th = thrh[h];
        float bb = bh[h];
        float mem = 0.f;
#pragma unroll
        for (int t = 0; t < T_STEPS; ++t) {
            float cur = acc2[t][j] + bb;
            float reset = (mem > th) ? th : 0.f;
            mem = be * mem + cur - reset;
            acc2[t][j] = ((mem - th) > 0.f) ? 1.f : 0.f;
        }
    }
    int rbase = blockIdx.x * 32 + tm * 8;
#pragma unroll
    for (int t = 0; t < T_STEPS; ++t) {
        float2 o = {acc2[t][0], acc2[t][1]};
        *(float2*)&spkh[(long)(rbase + t) * 128 + tn * 2] = o;
    }
}

// ---------------------------------------------------------------------------
// K3: cur_out[row=(t*64+b)][cls], reading spk_hid in t-minor layout.
// (unchanged — preserves the passing reduction order)
// ---------------------------------------------------------------------------
__global__ __launch_bounds__(256) void out_gemm(const float* __restrict__ spkh,
                                                const float* __restrict__ W_out,
                                                const float* __restrict__ b_out,
                                                float* __restrict__ cur_out) {
    __shared__ float part[256][8];
    int row = blockIdx.x;                    // t*64 + b
    int t = row >> 6, b = row & 63;
    int tid = threadIdx.x;
    float acc[6] = {0.f, 0.f, 0.f, 0.f, 0.f, 0.f};
    for (int j = tid; j < KFLAT; j += 256) {
        int n = j >> 7, h = j & 127;
        float s = spkh[((long)(b * NROW + n) * 8 + t) * 128 + h];
#pragma unroll
        for (int c = 0; c < 6; ++c)
            acc[c] = fmaf(s, W_out[c * KFLAT + j], acc[c]);
    }
#pragma unroll
    for (int c = 0; c < 6; ++c) part[tid][c] = acc[c];
    __syncthreads();
    for (int off = 128; off > 0; off >>= 1) {
        if (tid < off) {
#pragma unroll
            for (int c = 0; c < 6; ++c) part[tid][c] += part[tid + off][c];
        }
        __syncthreads();
    }
    if (tid < 6) cur_out[row * 6 + tid] = part[0][tid] + b_out[tid];
}

// ---------------------------------------------------------------------------
// K4: output-layer LIF (threshold 1.0), writes spikes (8,64,6) to d_out
// ---------------------------------------------------------------------------
__global__ void lif_out_kernel(const float* __restrict__ cur_out,
                               const float* __restrict__ beta_out,
                               float* __restrict__ out) {
    int j = threadIdx.x;                     // < 384, j = b*6 + cls
    if (j >= 384) return;
    int cls = j % 6;
    float be = fminf(fmaxf(beta_out[cls], 0.f), 1.f);
    float mem = 0.f;
#pragma unroll
    for (int t = 0; t < T_STEPS; ++t) {
        float cur = cur_out[t * 384 + j];
        float reset = (mem > 1.f) ? 1.f : 0.f;
        mem = be * mem + cur - reset;
        out[t * 384 + j] = ((mem - 1.f) > 0.f) ? 1.f : 0.f;
    }
}

extern "C" void kernel_launch(void* const* d_in, const int* in_sizes, int n_in,
                              void* d_out, int out_size, void* d_ws, size_t ws_size,
                              hipStream_t stream) {
    (void)in_sizes; (void)n_in; (void)out_size; (void)ws_size;
    const float* x        = (const float*)d_in[0];
    const float* W_in     = (const float*)d_in[1];
    const float* b_in     = (const float*)d_in[2];
    const float* W_hid    = (const float*)d_in[3];
    const float* b_hid    = (const float*)d_in[4];
    const float* W_out    = (const float*)d_in[5];
    const float* b_out    = (const float*)d_in[6];
    const float* beta_in  = (const float*)d_in[7];
    const float* thr_in   = (const float*)d_in[8];
    const float* beta_hid = (const float*)d_in[9];
    const float* thr_hid  = (const float*)d_in[10];
    const float* beta_out = (const float*)d_in[11];
    float* out = (float*)d_out;

    float* buf0 = (float*)d_ws;            // spk_hid: 21504*128 floats
    float* curo = buf0 + 2752512;          // 3,072 floats

    // 1. fused pool + fc_in + LIF + fc_hid + LIF: x -> spk_hid (buf0)
    snn_front<<<672, 256, 0, stream>>>(x, W_in, b_in, beta_in, thr_in,
                                       W_hid, b_hid, beta_hid, thr_hid, buf0);
    // 2. cur_out_all: (t,b) rows x 5376 -> 6
    out_gemm<<<512, 256, 0, stream>>>(buf0, W_out, b_out, curo);
    // 3. output LIF -> d_out
    lif_out_kernel<<<1, 384, 0, stream>>>(curo, beta_out, out);
}